// Round 5
// baseline (503.025 us; speedup 1.0000x reference)
//
#include <hip/hip_runtime.h>
#include <hip/hip_bf16.h>
#include <math.h>

#define D_MODEL 1024
#define NH 16
#define DK 64
#define BATCH 4
#define SEQ 1024
#define NEG_BIG (-1.0e30f)

typedef float f32x4 __attribute__((ext_vector_type(4)));
typedef short s16x8 __attribute__((ext_vector_type(8)));

// async global->LDS, 16 B per lane. LDS dest is wave-uniform base + lane*16.
__device__ __forceinline__ void gload_lds16(const void* g, void* l) {
    __builtin_amdgcn_global_load_lds((const __attribute__((address_space(1))) void*)g,
                                     (__attribute__((address_space(3))) void*)l, 16, 0, 0);
}

// ---------------------------------------------------------------------------
// All fp32->bf16 casts in ONE launch. Segments (8-elem units):
//   [0, 4*NW8)  : Wq,Wk,Wv,Wo   (NW8 = 2^17 each)
//   [4*NW8, ..) : query,key,value (NX8 = 2^19 each)
// ---------------------------------------------------------------------------
#define NW8 (D_MODEL * D_MODEL / 8)            // 131072 = 2^17
#define NX8 (BATCH * SEQ * D_MODEL / 8)        // 524288 = 2^19
__global__ __launch_bounds__(256) void cast_all(
        const float* __restrict__ Wq, const float* __restrict__ Wk,
        const float* __restrict__ Wv, const float* __restrict__ Wo,
        const float* __restrict__ q,  const float* __restrict__ k,
        const float* __restrict__ v,
        __hip_bfloat16* __restrict__ Wqb, __hip_bfloat16* __restrict__ Wkb,
        __hip_bfloat16* __restrict__ Wvb, __hip_bfloat16* __restrict__ Wob,
        __hip_bfloat16* __restrict__ Xq,  __hip_bfloat16* __restrict__ Xk,
        __hip_bfloat16* __restrict__ Xv) {
    int i = blockIdx.x * 256 + threadIdx.x;
    const float* src;
    __hip_bfloat16* dst;
    int o;
    if (i < 4 * NW8) {
        int seg = i >> 17; o = i & (NW8 - 1);
        src = seg == 0 ? Wq : seg == 1 ? Wk : seg == 2 ? Wv : Wo;
        dst = seg == 0 ? Wqb : seg == 1 ? Wkb : seg == 2 ? Wvb : Wob;
    } else {
        int j = i - 4 * NW8;
        int seg = j >> 19; o = j & (NX8 - 1);
        src = seg == 0 ? q : seg == 1 ? k : v;
        dst = seg == 0 ? Xq : seg == 1 ? Xk : Xv;
    }
    float4 x = ((const float4*)src)[2 * o];
    float4 y = ((const float4*)src)[2 * o + 1];
    alignas(16) __hip_bfloat16 ob[8];
    ob[0] = __float2bfloat16(x.x); ob[1] = __float2bfloat16(x.y);
    ob[2] = __float2bfloat16(x.z); ob[3] = __float2bfloat16(x.w);
    ob[4] = __float2bfloat16(y.x); ob[5] = __float2bfloat16(y.y);
    ob[6] = __float2bfloat16(y.z); ob[7] = __float2bfloat16(y.w);
    ((uint4*)dst)[o] = *(const uint4*)ob;
}

// ---------------------------------------------------------------------------
// bf16 MFMA GEMM body: C = A * Bt^T + bias. A: Mx1024, Bt: 1024x1024 row-major.
// 128x128 tile, BK=32, 4 waves in 2x2, each wave 4x4 mfma_f32_16x16x32_bf16.
// mode 0: fp32 row-major MxN out.
// mode 1: bf16 head-major (B,H,P,DK) out.
// mode 2: bf16 transposed head-major (B,H,DK,SEQ) out  (V^T for MFMA-PV).
// ---------------------------------------------------------------------------
__device__ __forceinline__ void gemm_body(const __hip_bfloat16* __restrict__ A,
                                          const __hip_bfloat16* __restrict__ Bt,
                                          const float* __restrict__ bias,
                                          void* __restrict__ Cout, int mode) {
    __shared__ __align__(16) __hip_bfloat16 As[128 * 32];
    __shared__ __align__(16) __hip_bfloat16 Bs[128 * 32];
    const int K = D_MODEL, N = D_MODEL;
    const int t    = threadIdx.x;
    const int lane = t & 63;
    const int w    = t >> 6;
    const int wm   = (w >> 1) * 64;
    const int wn   = (w & 1) * 64;
    const int rl   = lane & 15;
    const int g    = lane >> 4;
    const int row0 = blockIdx.y * 128;
    const int col0 = blockIdx.x * 128;

    f32x4 acc[4][4] = {};

    for (int k0 = 0; k0 < K; k0 += 32) {
#pragma unroll
        for (int i = 0; i < 2; i++) {
            int c = w * 128 + i * 64 + lane;   // 0..511
            int r = c >> 2, ko = (c & 3) * 8;  // [128 rows][4 chunks of 8 bf16]
            gload_lds16(A  + (size_t)(row0 + r) * K + k0 + ko,
                        As + (size_t)(w * 128 + i * 64) * 8);
            gload_lds16(Bt + (size_t)(col0 + r) * K + k0 + ko,
                        Bs + (size_t)(w * 128 + i * 64) * 8);
        }
        __syncthreads();
        s16x8 af[4], bf[4];
#pragma unroll
        for (int i = 0; i < 4; i++)
            af[i] = *(const s16x8*)&As[(wm + i * 16 + rl) * 32 + g * 8];
#pragma unroll
        for (int j = 0; j < 4; j++)
            bf[j] = *(const s16x8*)&Bs[(wn + j * 16 + rl) * 32 + g * 8];
#pragma unroll
        for (int i = 0; i < 4; i++)
#pragma unroll
            for (int j = 0; j < 4; j++)
                acc[i][j] = __builtin_amdgcn_mfma_f32_16x16x32_bf16(af[i], bf[j], acc[i][j], 0, 0, 0);
        __syncthreads();
    }

    // C/D layout: col = lane&15, row = (lane>>4)*4 + reg  [m89/m91 verified]
    if (mode == 0) {
        float* C = (float*)Cout;
#pragma unroll
        for (int j = 0; j < 4; j++) {
            int c = col0 + wn + j * 16 + rl;
            float bv = bias[c];
#pragma unroll
            for (int i = 0; i < 4; i++) {
                int rbase = row0 + wm + i * 16 + g * 4;
#pragma unroll
                for (int r = 0; r < 4; r++)
                    C[(size_t)(rbase + r) * N + c] = acc[i][j][r] + bv;
            }
        }
    } else if (mode == 1) {
        __hip_bfloat16* C = (__hip_bfloat16*)Cout;
#pragma unroll
        for (int j = 0; j < 4; j++) {
            int c = col0 + wn + j * 16 + rl;
            float bv = bias[c];
            int h = c >> 6, d = c & 63;
#pragma unroll
            for (int i = 0; i < 4; i++) {
                int rbase = row0 + wm + i * 16 + g * 4;
#pragma unroll
                for (int r = 0; r < 4; r++) {
                    int m = rbase + r;
                    int b = m >> 10, p = m & (SEQ - 1);
                    C[(((size_t)b * NH + h) * SEQ + p) * DK + d] =
                        __float2bfloat16(acc[i][j][r] + bv);
                }
            }
        }
    } else {
        // mode 2: V^T head-major (B,H,DK,SEQ), 4 consecutive p packed per store
        __hip_bfloat16* C = (__hip_bfloat16*)Cout;
#pragma unroll
        for (int j = 0; j < 4; j++) {
            int c = col0 + wn + j * 16 + rl;
            float bv = bias[c];
            int h = c >> 6, d = c & 63;
#pragma unroll
            for (int i = 0; i < 4; i++) {
                int rbase = row0 + wm + i * 16 + g * 4;
                int b = rbase >> 10, p = rbase & (SEQ - 1);
                alignas(8) __hip_bfloat16 o4[4];
#pragma unroll
                for (int r = 0; r < 4; r++)
                    o4[r] = __float2bfloat16(acc[i][j][r] + bv);
                *(uint2*)&C[(((size_t)b * NH + h) * DK + d) * SEQ + p] = *(const uint2*)o4;
            }
        }
    }
}

__global__ __launch_bounds__(256) void gemm_bf16(const __hip_bfloat16* __restrict__ A,
                                                 const __hip_bfloat16* __restrict__ Bt,
                                                 const float* __restrict__ bias,
                                                 void* __restrict__ Cout, int mode) {
    gemm_body(A, Bt, bias, Cout, mode);
}

// Batched Q/K/V projections: gridDim.z selects which projection this block does.
__global__ __launch_bounds__(256) void gemm_qkv(
        const __hip_bfloat16* __restrict__ Xq, const __hip_bfloat16* __restrict__ Xk,
        const __hip_bfloat16* __restrict__ Xv,
        const __hip_bfloat16* __restrict__ Wqb, const __hip_bfloat16* __restrict__ Wkb,
        const __hip_bfloat16* __restrict__ Wvb,
        const float* __restrict__ bq, const float* __restrict__ bk,
        const float* __restrict__ bv,
        __hip_bfloat16* __restrict__ qhm, __hip_bfloat16* __restrict__ khm,
        __hip_bfloat16* __restrict__ vtb) {
    if (blockIdx.z == 0)      gemm_body(Xq, Wqb, bq, qhm, 1);
    else if (blockIdx.z == 1) gemm_body(Xk, Wkb, bk, khm, 1);
    else                      gemm_body(Xv, Wvb, bv, vtb, 2);
}

// ---------------------------------------------------------------------------
// FUSED attention: per (bh, 128-row q-tile), loop over causal kj tiles:
//   swapped QK^T MFMA (mfma(K,Q): lane holds 4 CONSECUTIVE k-cols ->
//   float4 S stores + packed b64 P->LDS writes), max-free softmax
//   (exp(S), row sums in 4 register partials; k is the in-lane dim),
//   PV MFMA from XOR-swizzled LDS (byte ^= (row&7)<<4 kills the 256B-stride
//   32-way bank conflict on both P[128][128] and V^T[64][128] bf16 tiles).
// Q-frags loaded ONCE into regs; K-frags straight from global per tile
// (khm per bh = 128 KB, L2-resident). Upper (masked) S tiles filled after.
// LDS 50.7 KB -> 3 blocks/CU. Output ctx bf16 in (token, d_model) layout.
// ---------------------------------------------------------------------------
__global__ __launch_bounds__(256) void attn_fused(const __hip_bfloat16* __restrict__ qhm,
                                                  const __hip_bfloat16* __restrict__ khm,
                                                  const __hip_bfloat16* __restrict__ vt,
                                                  float* __restrict__ S,
                                                  __hip_bfloat16* __restrict__ ctx) {
    __shared__ __align__(16) char Psb[128 * 256];   // P bf16 [128 q][128 k], swizzled
    __shared__ __align__(16) char Vsb[64 * 256];    // V^T bf16 [64 d][128 k], swizzled
    __shared__ float lpartial[2][128];
    __shared__ float lrow[128];
    const int t  = threadIdx.x;
    const int bh = blockIdx.y;
    const int b  = bh >> 4;
    const int h  = bh & 15;
    const int qt = blockIdx.x;            // q-tile 0..7
    const int qi0 = qt * 128;
    float* Sb = S + (size_t)bh * SEQ * SEQ;
    const __hip_bfloat16* qb = qhm + (size_t)bh * SEQ * DK;
    const __hip_bfloat16* kb = khm + (size_t)bh * SEQ * DK;
    const __hip_bfloat16* vb = vt + (size_t)bh * DK * SEQ;

    const int lane = t & 63;
    const int w    = t >> 6;
    const int rl   = lane & 15;
    const int g    = lane >> 4;
    // QK^T (swapped) wave mapping: q-block qo, k-block ko2
    const int qo  = (w & 1) * 64;
    const int ko2 = (w >> 1) * 64;
    // PV wave mapping (as before): q rows wm, d cols wn
    const int wm = (w >> 1) * 64;
    const int wn = (w & 1) * 32;
    const int sw = (rl & 7) << 4;         // LDS XOR swizzle for this lane's rows

    // Q-fragments once (B-operand of swapped QK): rows qi0+qo+j*16+rl
    s16x8 bfQ[2][4];
#pragma unroll
    for (int s = 0; s < 2; s++)
#pragma unroll
        for (int j = 0; j < 4; j++)
            bfQ[s][j] = *(const s16x8*)&qb[(size_t)(qi0 + qo + j * 16 + rl) * DK + s * 32 + g * 8];

    float lpart[4] = {0.f, 0.f, 0.f, 0.f};
    f32x4 acc[4][2] = {};
    const float scale = 0.125f;

    for (int jt = 0; jt <= qt; jt++) {
        const int kj0 = jt * 128;
        // K-fragments from global (A-operand): rows kj0+ko2+i*16+rl
        s16x8 afK[2][4];
#pragma unroll
        for (int s = 0; s < 2; s++)
#pragma unroll
            for (int i = 0; i < 4; i++)
                afK[s][i] = *(const s16x8*)&kb[(size_t)(kj0 + ko2 + i * 16 + rl) * DK + s * 32 + g * 8];
        // V^T tile loads (independent; overlap with MFMA)
        uint4 vr[4];
#pragma unroll
        for (int it = 0; it < 4; it++) {
            int idx = it * 256 + t;
            int r = idx >> 4, c = idx & 15;
            vr[it] = *(const uint4*)&vb[(size_t)r * SEQ + kj0 + c * 8];
        }
        // swapped QK^T: s2[i][j] holds S[q=qo+j*16+rl][k=ko2+i*16+g*4+r]
        f32x4 s2[4][4] = {};
#pragma unroll
        for (int s = 0; s < 2; s++)
#pragma unroll
            for (int i = 0; i < 4; i++)
#pragma unroll
                for (int j = 0; j < 4; j++)
                    s2[i][j] = __builtin_amdgcn_mfma_f32_16x16x32_bf16(afK[s][i], bfQ[s][j], s2[i][j], 0, 0, 0);
        // V^T -> swizzled LDS
#pragma unroll
        for (int it = 0; it < 4; it++) {
            int idx = it * 256 + t;
            int r = idx >> 4, c = idx & 15;
            *(uint4*)(Vsb + ((r * 256 + c * 16) ^ ((r & 7) << 4))) = vr[it];
        }
        // S store (float4), exp, P -> swizzled LDS (b64), row partials
#pragma unroll
        for (int i = 0; i < 4; i++) {
            int kjb = kj0 + ko2 + i * 16 + g * 4;
#pragma unroll
            for (int j = 0; j < 4; j++) {
                int qi = qi0 + qo + j * 16 + rl;
                float4 sv;
                float p4[4], sum = 0.f;
#pragma unroll
                for (int r = 0; r < 4; r++) {
                    float sc = s2[i][j][r] * scale;
                    bool ok = (kjb + r) <= qi;
                    ((float*)&sv)[r] = ok ? sc : NEG_BIG;
                    float pe = ok ? __expf(sc) : 0.f;
                    p4[r] = pe;
                    sum += pe;
                }
                *(float4*)&Sb[(size_t)qi * SEQ + kjb] = sv;
                lpart[j] += sum;
                alignas(8) __hip_bfloat16 pb[4];
#pragma unroll
                for (int r = 0; r < 4; r++) pb[r] = __float2bfloat16(p4[r]);
                int qrow = qo + j * 16 + rl;
                int kcol = ko2 + i * 16 + g * 4;
                *(uint2*)(Psb + ((qrow * 256 + kcol * 2) ^ sw)) = *(const uint2*)pb;
            }
        }
        __syncthreads();
        // PV MFMA from LDS
#pragma unroll
        for (int kk = 0; kk < 4; kk++) {
            s16x8 afP[4], bfV[2];
#pragma unroll
            for (int i = 0; i < 4; i++)
                afP[i] = *(const s16x8*)(Psb + (((wm + i * 16 + rl) * 256 + kk * 64 + g * 16) ^ sw));
#pragma unroll
            for (int j = 0; j < 2; j++)
                bfV[j] = *(const s16x8*)(Vsb + (((wn + j * 16 + rl) * 256 + kk * 64 + g * 16) ^ sw));
#pragma unroll
            for (int i = 0; i < 4; i++)
#pragma unroll
                for (int j = 0; j < 2; j++)
                    acc[i][j] = __builtin_amdgcn_mfma_f32_16x16x32_bf16(afP[i], bfV[j], acc[i][j], 0, 0, 0);
        }
        __syncthreads();
    }

    // fill fully-masked upper tiles of S
    {
        float4 neg4 = make_float4(NEG_BIG, NEG_BIG, NEG_BIG, NEG_BIG);
        for (int jt = qt + 1; jt < SEQ / 128; jt++) {
#pragma unroll
            for (int it = 0; it < 16; it++) {
                int idx = it * 256 + t;
                int r = idx >> 5, c4 = idx & 31;
                *(float4*)&Sb[(size_t)(qi0 + r) * SEQ + jt * 128 + c4 * 4] = neg4;
            }
        }
    }

    // row-sum finalize: butterfly over lane bits 4,5 (the k-chunk dim),
    // then combine the two k-half waves via LDS.
#pragma unroll
    for (int j = 0; j < 4; j++) {
        float v = lpart[j];
        v += __shfl_xor(v, 16, 64);
        v += __shfl_xor(v, 32, 64);
        if (g == 0) lpartial[w >> 1][qo + j * 16 + rl] = v;
    }
    __syncthreads();
    if (t < 128) lrow[t] = lpartial[0][t] + lpartial[1][t];
    __syncthreads();

    // normalize, write ctx bf16 into [b*SEQ+p][h*64+d]
#pragma unroll
    for (int i = 0; i < 4; i++) {
#pragma unroll
        for (int r = 0; r < 4; r++) {
            int pl = wm + i * 16 + g * 4 + r;
            float il = 1.0f / lrow[pl];
            int p = qi0 + pl;
#pragma unroll
            for (int j = 0; j < 2; j++) {
                int d = wn + j * 16 + rl;
                ctx[((size_t)(b * SEQ + p)) * D_MODEL + h * 64 + d] =
                    __float2bfloat16(acc[i][j][r] * il);
            }
        }
    }
}

// ---------------------------------------------------------------------------
extern "C" void kernel_launch(void* const* d_in, const int* in_sizes, int n_in,
                              void* d_out, int out_size, void* d_ws, size_t ws_size,
                              hipStream_t stream) {
    const float* query = (const float*)d_in[0];
    const float* key_  = (const float*)d_in[1];
    const float* value = (const float*)d_in[2];
    const float* Wq    = (const float*)d_in[3];
    const float* bq    = (const float*)d_in[4];
    const float* Wk    = (const float*)d_in[5];
    const float* bk    = (const float*)d_in[6];
    const float* Wv    = (const float*)d_in[7];
    const float* bv    = (const float*)d_in[8];
    const float* Wo    = (const float*)d_in[9];
    const float* bo    = (const float*)d_in[10];

    const size_t MB   = 1024 * 1024;
    const int    NTOK = BATCH * SEQ;                      // 4096
    char* wsb = (char*)d_ws;
    __hip_bfloat16* Xq  = (__hip_bfloat16*)wsb;               // 8 MB (ctx reuses this)
    __hip_bfloat16* Xk  = (__hip_bfloat16*)(wsb + 8  * MB);   // 8 MB
    __hip_bfloat16* Xv  = (__hip_bfloat16*)(wsb + 16 * MB);   // 8 MB
    __hip_bfloat16* Wqb = (__hip_bfloat16*)(wsb + 24 * MB);
    __hip_bfloat16* Wkb = (__hip_bfloat16*)(wsb + 26 * MB);
    __hip_bfloat16* Wvb = (__hip_bfloat16*)(wsb + 28 * MB);
    __hip_bfloat16* Wob = (__hip_bfloat16*)(wsb + 30 * MB);
    __hip_bfloat16* qhm = (__hip_bfloat16*)(wsb + 32 * MB);   // 8 MB (B,H,P,DK)
    __hip_bfloat16* khm = (__hip_bfloat16*)(wsb + 40 * MB);   // 8 MB
    __hip_bfloat16* Vtb = (__hip_bfloat16*)(wsb + 48 * MB);   // 8 MB (B,H,DK,SEQ)
    __hip_bfloat16* ctx = Xq;                                 // Xq dead after QKV GEMM

    float* out    = (float*)d_out;
    float* scores = out + (size_t)NTOK * D_MODEL;

    // single cast kernel: 4 weight segs + 3 activation segs
    cast_all<<<(4 * NW8 + 3 * NX8) / 256, 256, 0, stream>>>(
        Wq, Wk, Wv, Wo, query, key_, value,
        Wqb, Wkb, Wvb, Wob, Xq, Xk, Xv);

    dim3 pgrid(D_MODEL / 128, NTOK / 128);                // (8, 32)

    // batched QKV projections: 768 blocks in one launch
    gemm_qkv<<<dim3(D_MODEL / 128, NTOK / 128, 3), 256, 0, stream>>>(
        Xq, Xk, Xv, Wqb, Wkb, Wvb, bq, bk, bv, qhm, khm, Vtb);

    // fused scores + softmax + PV (writes S to output, ctx to Xq buffer)
    attn_fused<<<dim3(SEQ / 128, BATCH * NH), 256, 0, stream>>>(
        qhm, khm, Vtb, scores, ctx);

    gemm_bf16<<<pgrid, 256, 0, stream>>>(ctx, Wob, bo, out, 0);
}